// Round 1
// baseline (4858.384 us; speedup 1.0000x reference)
//
#include <hip/hip_runtime.h>
#include <math.h>

#define BB 16
#define DTOT 544
#define TT_DIM 4096
#define DS 512
#define NCODES 4096
#define HALFV 7.5f
#define EPSV 1e-5f

#define TT 32      // t per block in argmin
#define CC 128     // codes per chunk
#define KC 32      // K per LDS stage

// ---------------- kernel A: emb, embT, e2 ----------------
__global__ __launch_bounds__(256) void k_emb(const float* __restrict__ esum,
                                             const float* __restrict__ usage,
                                             float* __restrict__ emb,
                                             float* __restrict__ embT,
                                             float* __restrict__ e2) {
    int c = blockIdx.x;
    float u = usage[c];
    u = (u < EPSV) ? EPSV : u;
    float s = 0.f;
#pragma unroll
    for (int i = 0; i < 2; i++) {
        int d = threadIdx.x + i * 256;
        float v = esum[(size_t)c * DS + d] / u;
        emb[(size_t)c * DS + d] = v;
        embT[(size_t)d * NCODES + c] = v;
        s += v * v;
    }
#pragma unroll
    for (int o = 32; o; o >>= 1) s += __shfl_down(s, o, 64);
    __shared__ float red[4];
    if ((threadIdx.x & 63) == 0) red[threadIdx.x >> 6] = s;
    __syncthreads();
    if (threadIdx.x == 0) e2[c] = red[0] + red[1] + red[2] + red[3];
}

// ---------------- kernel B: argmin over codes (GEMM-like) ----------------
__global__ __launch_bounds__(256, 2) void k_argmin(const float* __restrict__ x,
                                                   const float* __restrict__ embT,
                                                   const float* __restrict__ e2,
                                                   int* __restrict__ codes,
                                                   int* __restrict__ cand2,
                                                   float* __restrict__ margin) {
    __shared__ float xs[DS * TT];   // 64 KB, xs[d*32 + tt]
    __shared__ float es[KC * CC];   // 16 KB, es[dk*128 + c]

    int b = blockIdx.y;
    int t0 = blockIdx.x * TT;
    const float* xb = x + (size_t)b * DTOT * TT_DIM + t0;

    // load x tile (float4 over t)
#pragma unroll
    for (int i = 0; i < 16; i++) {
        int d = (threadIdx.x >> 3) + i * 32;
        int tt4 = threadIdx.x & 7;
        *(float4*)&xs[d * TT + tt4 * 4] =
            *(const float4*)&xb[(size_t)d * TT_DIM + tt4 * 4];
    }

    int tg = threadIdx.x & 7;    // t-group: t = tg*4 + i
    int cg = threadIdx.x >> 3;   // code-group: c = cg*4 + j (within chunk)

    float best[4], sec[4];
    int bi[4], si[4];
#pragma unroll
    for (int i = 0; i < 4; i++) { best[i] = 3.4e38f; sec[i] = 3.4e38f; bi[i] = 0; si[i] = 0; }

    for (int c0 = 0; c0 < NCODES; c0 += CC) {
        float4 a0 = {0,0,0,0}, a1 = {0,0,0,0}, a2 = {0,0,0,0}, a3 = {0,0,0,0};
        for (int k0 = 0; k0 < DS; k0 += KC) {
            __syncthreads();
#pragma unroll
            for (int i = 0; i < 4; i++) {
                int dk = (threadIdx.x >> 5) + i * 8;
                int c4 = threadIdx.x & 31;
                *(float4*)&es[dk * CC + c4 * 4] =
                    *(const float4*)&embT[(size_t)(k0 + dk) * NCODES + c0 + c4 * 4];
            }
            __syncthreads();
#pragma unroll
            for (int dk = 0; dk < KC; dk++) {
                float4 xv = *(const float4*)&xs[(k0 + dk) * TT + tg * 4];
                float4 ev = *(const float4*)&es[dk * CC + cg * 4];
                a0.x = fmaf(xv.x, ev.x, a0.x); a0.y = fmaf(xv.x, ev.y, a0.y);
                a0.z = fmaf(xv.x, ev.z, a0.z); a0.w = fmaf(xv.x, ev.w, a0.w);
                a1.x = fmaf(xv.y, ev.x, a1.x); a1.y = fmaf(xv.y, ev.y, a1.y);
                a1.z = fmaf(xv.y, ev.z, a1.z); a1.w = fmaf(xv.y, ev.w, a1.w);
                a2.x = fmaf(xv.z, ev.x, a2.x); a2.y = fmaf(xv.z, ev.y, a2.y);
                a2.z = fmaf(xv.z, ev.z, a2.z); a2.w = fmaf(xv.z, ev.w, a2.w);
                a3.x = fmaf(xv.w, ev.x, a3.x); a3.y = fmaf(xv.w, ev.y, a3.y);
                a3.z = fmaf(xv.w, ev.z, a3.z); a3.w = fmaf(xv.w, ev.w, a3.w);
            }
        }
        float4 e2v = *(const float4*)&e2[c0 + cg * 4];
        int cbase = c0 + cg * 4;
        float d2v[4][4] = {
            {e2v.x - 2.f*a0.x, e2v.y - 2.f*a0.y, e2v.z - 2.f*a0.z, e2v.w - 2.f*a0.w},
            {e2v.x - 2.f*a1.x, e2v.y - 2.f*a1.y, e2v.z - 2.f*a1.z, e2v.w - 2.f*a1.w},
            {e2v.x - 2.f*a2.x, e2v.y - 2.f*a2.y, e2v.z - 2.f*a2.z, e2v.w - 2.f*a2.w},
            {e2v.x - 2.f*a3.x, e2v.y - 2.f*a3.y, e2v.z - 2.f*a3.z, e2v.w - 2.f*a3.w}};
#pragma unroll
        for (int i = 0; i < 4; i++) {
#pragma unroll
            for (int j = 0; j < 4; j++) {
                float v = d2v[i][j];
                int vi = cbase + j;
                if (v < best[i]) { sec[i] = best[i]; si[i] = bi[i]; best[i] = v; bi[i] = vi; }
                else if (v < sec[i]) { sec[i] = v; si[i] = vi; }
            }
        }
    }

    // cross-thread reduction over code-groups (reuse xs)
    __syncthreads();
    float* rb = xs;
    float* rs = xs + 1024;
    int* rbi = (int*)(xs + 2048);
    int* rsi = (int*)(xs + 3072);
#pragma unroll
    for (int i = 0; i < 4; i++) {
        int slot = (tg * 4 + i) * 32 + cg;
        rb[slot] = best[i]; rs[slot] = sec[i];
        rbi[slot] = bi[i];  rsi[slot] = si[i];
    }
    __syncthreads();
    if (threadIdx.x < 32) {
        int t = threadIdx.x;
        float b_ = 3.4e38f, s_ = 3.4e38f;
        int bi_ = 0, si_ = 0;
        for (int g = 0; g < 32; g++) {
            int slot = t * 32 + g;
            float v = rb[slot]; int vi = rbi[slot];
            if (v < b_) { s_ = b_; si_ = bi_; b_ = v; bi_ = vi; }
            else if (v < s_) { s_ = v; si_ = vi; }
            float w = rs[slot]; int wi = rsi[slot];
            if (w < b_) { s_ = b_; si_ = bi_; b_ = w; bi_ = wi; }
            else if (w < s_) { s_ = w; si_ = wi; }
        }
        int row = b * TT_DIM + t0 + t;
        codes[row] = bi_;
        cand2[row] = si_;
        margin[row] = s_ - b_;
    }
}

// ---------------- kernel B2: fp64 refinement of near-ties ----------------
__global__ __launch_bounds__(256) void k_refine(const float* __restrict__ x,
                                                const float* __restrict__ emb,
                                                int* __restrict__ codes,
                                                const int* __restrict__ cand2,
                                                const float* __restrict__ margin) {
    int wid = threadIdx.x >> 6, lane = threadIdx.x & 63;
    int row = blockIdx.x * 4 + wid;
    if (margin[row] > 0.01f) return;
    int b = row >> 12;
    int t = row & 4095;
    int c1 = codes[row], c2 = cand2[row];
    const float* xb = x + (size_t)b * DTOT * TT_DIM + t;
    double s1 = 0.0, s2 = 0.0;
    for (int d = lane; d < DS; d += 64) {
        double xv = (double)xb[(size_t)d * TT_DIM];
        double d1 = xv - (double)emb[(size_t)c1 * DS + d];
        double d2 = xv - (double)emb[(size_t)c2 * DS + d];
        s1 += d1 * d1;
        s2 += d2 * d2;
    }
#pragma unroll
    for (int o = 32; o; o >>= 1) { s1 += __shfl_down(s1, o, 64); s2 += __shfl_down(s2, o, 64); }
    if (lane == 0) {
        if (s2 < s1 || (s2 == s1 && c2 < c1)) codes[row] = c2;
    }
}

// ---------------- kernel C: sem output (gather or copy) + sem codes ----------------
__global__ __launch_bounds__(256) void k_sem(const float* __restrict__ x,
                                             const float* __restrict__ emb,
                                             const int* __restrict__ codes,
                                             const float* __restrict__ sem_probs,
                                             float* __restrict__ out) {
    __shared__ float q[TT * (DS + 1)];
    __shared__ int rowc[TT];
    int b = blockIdx.y, t0 = blockIdx.x * TT;
    bool mask = sem_probs[b] < 0.5f;
    float* outb = out + (size_t)b * DTOT * TT_DIM + t0;
    const float* xb = x + (size_t)b * DTOT * TT_DIM + t0;
    const size_t QOFF = (size_t)BB * DTOT * TT_DIM;

    if (threadIdx.x < TT) {
        int code = codes[b * TT_DIM + t0 + threadIdx.x];
        rowc[threadIdx.x] = code;
        out[QOFF + ((size_t)b * 33) * TT_DIM + t0 + threadIdx.x] = (float)code;
    }
    __syncthreads();

    if (mask) {
        for (int i = 0; i < TT * DS / 256; i++) {
            int idx = threadIdx.x + i * 256;
            int tt = idx >> 9, d = idx & 511;
            q[tt * (DS + 1) + d] = emb[(size_t)rowc[tt] * DS + d];
        }
        __syncthreads();
        for (int i = 0; i < TT * DS / 256; i++) {
            int idx = threadIdx.x + i * 256;
            int d = idx >> 5, tt = idx & 31;
            outb[(size_t)d * TT_DIM + tt] = q[tt * (DS + 1) + d];
        }
    } else {
        for (int i = 0; i < TT * DS / 256; i++) {
            int idx = threadIdx.x + i * 256;
            int d = idx >> 5, tt = idx & 31;
            outb[(size_t)d * TT_DIM + tt] = xb[(size_t)d * TT_DIM + tt];
        }
    }
}

// ---------------- kernel D: aco elementwise ----------------
__global__ __launch_bounds__(256) void k_aco(const float* __restrict__ x,
                                             const float* __restrict__ noise,
                                             const float* __restrict__ aco_probs,
                                             float* __restrict__ out) {
    int idx = blockIdx.x * 256 + threadIdx.x;   // one float4 per thread
    int t4 = idx & 1023;
    int bc = idx >> 10;
    int ch = bc & 31;
    int b = bc >> 5;
    const float4 xv = *(const float4*)&x[((size_t)(b * DTOT + DS + ch)) * TT_DIM + t4 * 4];
    const float4 nv = *(const float4*)&noise[((size_t)(b * 32 + ch)) * TT_DIM + t4 * 4];
    float p = aco_probs[b];
    const size_t QOFF = (size_t)BB * DTOT * TT_DIM;

    float zq[4], cq[4];
    float xa[4] = {xv.x, xv.y, xv.z, xv.w};
    float na[4] = {nv.x, nv.y, nv.z, nv.w};
#pragma unroll
    for (int i = 0; i < 4; i++) {
        float zb = tanhf(xa[i]) * HALFV;
        float z;
        if (p < 0.5f) z = rintf(zb);
        else if (p < 0.75f) z = fminf(fmaxf(zb + na[i], -HALFV), HALFV);
        else z = zb;
        zq[i] = z / HALFV;
        cq[i] = fminf(fmaxf(rintf(z + HALFV), 0.f), 15.f);
    }
    float4 qo = {zq[0], zq[1], zq[2], zq[3]};
    float4 co = {cq[0], cq[1], cq[2], cq[3]};
    *(float4*)&out[((size_t)(b * DTOT + DS + ch)) * TT_DIM + t4 * 4] = qo;
    *(float4*)&out[QOFF + ((size_t)(b * 33 + 1 + ch)) * TT_DIM + t4 * 4] = co;
}

extern "C" void kernel_launch(void* const* d_in, const int* in_sizes, int n_in,
                              void* d_out, int out_size, void* d_ws, size_t ws_size,
                              hipStream_t stream) {
    const float* x         = (const float*)d_in[0];
    const float* esum      = (const float*)d_in[1];
    const float* usage     = (const float*)d_in[2];
    const float* sem_probs = (const float*)d_in[3];
    const float* aco_probs = (const float*)d_in[4];
    const float* noise     = (const float*)d_in[5];
    float* out = (float*)d_out;

    float* ws = (float*)d_ws;
    float* emb    = ws;                                  // 4096*512
    float* embT   = ws + (size_t)NCODES * DS;            // 512*4096
    float* e2     = ws + (size_t)2 * NCODES * DS;        // 4096
    int*   codes  = (int*)(ws + (size_t)2 * NCODES * DS + NCODES);          // 65536
    int*   cand2  = codes + (size_t)BB * TT_DIM;                            // 65536
    float* margin = (float*)(cand2 + (size_t)BB * TT_DIM);                  // 65536

    k_emb<<<NCODES, 256, 0, stream>>>(esum, usage, emb, embT, e2);
    k_argmin<<<dim3(TT_DIM / TT, BB), 256, 0, stream>>>(x, embT, e2, codes, cand2, margin);
    k_refine<<<(BB * TT_DIM) / 4, 256, 0, stream>>>(x, emb, codes, cand2, margin);
    k_sem<<<dim3(TT_DIM / TT, BB), 256, 0, stream>>>(x, emb, codes, sem_probs, out);
    k_aco<<<(BB * 32 * TT_DIM) / (256 * 4), 256, 0, stream>>>(x, noise, aco_probs, out);
}

// Round 2
// 1394.304 us; speedup vs baseline: 3.4845x; 3.4845x over previous
//
#include <hip/hip_runtime.h>
#include <math.h>

#define BB 16
#define DTOT 544
#define TT_DIM 4096
#define DS 512
#define NCODES 4096
#define HALFV 7.5f
#define EPSV 1e-5f
#define NROWS (BB * TT_DIM)          // 65536
#define NT_TILES 32                  // 4096 / 128
#define MT_TILES 512                 // 65536 / 128
#define KT_TILES 24                  // 1536 / 64
#define TILE_BYTES 16384             // 128 x 64 bf16
#define REFINE_THR 0.05f
#define TT 32                        // t per block in k_sem

typedef short bf16x8 __attribute__((ext_vector_type(8)));
typedef float f32x4 __attribute__((ext_vector_type(4)));

__device__ __forceinline__ unsigned short f2bf(float v) {
    unsigned u = __float_as_uint(v);
    unsigned r = (u + 0x7fffu + ((u >> 16) & 1u)) >> 16;
    return (unsigned short)r;
}
__device__ __forceinline__ float bf2f(unsigned short h) {
    return __uint_as_float((unsigned)h << 16);
}

// ---------------- kernel: emb fp32 + e2 + zero flag counter ----------------
__global__ __launch_bounds__(256) void k_emb(const float* __restrict__ esum,
                                             const float* __restrict__ usage,
                                             float* __restrict__ emb,
                                             float* __restrict__ e2,
                                             int* __restrict__ counter) {
    int c = blockIdx.x;
    if (c == 0 && threadIdx.x == 0) *counter = 0;
    float u = usage[c];
    u = (u < EPSV) ? EPSV : u;
    float s = 0.f;
#pragma unroll
    for (int i = 0; i < 2; i++) {
        int d = threadIdx.x + i * 256;
        float v = esum[(size_t)c * DS + d] / u;
        emb[(size_t)c * DS + d] = v;
        s += v * v;
    }
#pragma unroll
    for (int o = 32; o; o >>= 1) s += __shfl_down(s, o, 64);
    __shared__ float red[4];
    if ((threadIdx.x & 63) == 0) red[threadIdx.x >> 6] = s;
    __syncthreads();
    if (threadIdx.x == 0) e2[c] = red[0] + red[1] + red[2] + red[3];
}

// ---------------- kernel: pack A (x sem part) into swizzled bf16 hi/lo tiles ----------------
// A tiles: [mt][akt] 16KB each; akt 0..7 = xh d-chunks, 8..15 = xl d-chunks.
// In-tile layout: byte = row*128 + ((u ^ (row&7))<<4) + (k&7)*2, u = k>>3.
__global__ __launch_bounds__(256) void k_packA(const float* __restrict__ x,
                                               char* __restrict__ Ap) {
    __shared__ char ldsH[TILE_BYTES];
    __shared__ char ldsL[TILE_BYTES];
    int mt = blockIdx.x, dc = blockIdx.y;
    int b = mt >> 5;
    int t0 = (mt & 31) * 128;
    int tid = threadIdx.x;
#pragma unroll
    for (int i = 0; i < 8; i++) {
        int idx = tid + i * 256;
        int dof = idx >> 5;          // 0..63
        int f4 = idx & 31;           // t-float4 0..31
        float4 v = *(const float4*)&x[((size_t)b * DTOT + dc * 64 + dof) * TT_DIM + t0 + f4 * 4];
        float va[4] = {v.x, v.y, v.z, v.w};
        int u = dof >> 3;
#pragma unroll
        for (int j = 0; j < 4; j++) {
            int row = f4 * 4 + j;
            unsigned short hi = f2bf(va[j]);
            unsigned short lo = f2bf(va[j] - bf2f(hi));
            int off = row * 128 + ((u ^ (row & 7)) << 4) + (dof & 7) * 2;
            *(unsigned short*)&ldsH[off] = hi;
            *(unsigned short*)&ldsL[off] = lo;
        }
    }
    __syncthreads();
    char* gH = Ap + ((size_t)mt * 16 + dc) * TILE_BYTES;
    char* gL = Ap + ((size_t)mt * 16 + 8 + dc) * TILE_BYTES;
#pragma unroll
    for (int i = 0; i < 4; i++) {
        int off = (tid + i * 256) * 16;
        *(uint4*)&gH[off] = *(const uint4*)&ldsH[off];
        *(uint4*)&gL[off] = *(const uint4*)&ldsL[off];
    }
}

// ---------------- kernel: pack B (emb) into swizzled bf16 tiles, K-layout [eh|el|eh] ----------------
__global__ __launch_bounds__(256) void k_packB(const float* __restrict__ emb,
                                               char* __restrict__ Bp) {
    __shared__ char ldsT[TILE_BYTES];
    int nt = blockIdx.x, kt = blockIdx.y;
    int c0 = nt * 128;
    int lo_flag = (kt >= 8 && kt < 16);
    int d0 = ((kt < 8) ? kt : ((kt < 16) ? kt - 8 : kt - 16)) * 64;
    int tid = threadIdx.x;
#pragma unroll
    for (int i = 0; i < 8; i++) {
        int idx = tid + i * 256;
        int row = idx >> 4;          // code 0..127
        int f4 = idx & 15;           // d-float4 0..15
        float4 v = *(const float4*)&emb[(size_t)(c0 + row) * DS + d0 + f4 * 4];
        float va[4] = {v.x, v.y, v.z, v.w};
        unsigned short w[4];
#pragma unroll
        for (int j = 0; j < 4; j++) {
            unsigned short hi = f2bf(va[j]);
            w[j] = lo_flag ? f2bf(va[j] - bf2f(hi)) : hi;
        }
        int u = f4 >> 1;
        int off = row * 128 + ((u ^ (row & 7)) << 4) + (f4 & 1) * 8;
        uint2 pk;
        pk.x = ((unsigned)w[1] << 16) | w[0];
        pk.y = ((unsigned)w[3] << 16) | w[2];
        *(uint2*)&ldsT[off] = pk;
    }
    __syncthreads();
    char* g = Bp + ((size_t)nt * KT_TILES + kt) * TILE_BYTES;
#pragma unroll
    for (int i = 0; i < 4; i++) {
        int off = (tid + i * 256) * 16;
        *(uint4*)&g[off] = *(const uint4*)&ldsT[off];
    }
}

// ---------------- kernel: MFMA distance-argmin ----------------
// grid (32 nt, 512 mt); block 256 = 4 waves (2x2), each wave 64x64 output.
__global__ __launch_bounds__(256) void k_mfma(const char* __restrict__ Ap,
                                              const char* __restrict__ Bp,
                                              const float* __restrict__ e2,
                                              float* __restrict__ pb,
                                              int* __restrict__ pi,
                                              float* __restrict__ ps) {
    __shared__ char lds[32768];  // A [0,16K), B [16K,32K)
    int nt = blockIdx.x, mt = blockIdx.y;
    int tid = threadIdx.x;
    int lane = tid & 63;
    int w = tid >> 6;
    int wr = w >> 1, wc = w & 1;

    f32x4 acc[4][4];
#pragma unroll
    for (int m = 0; m < 4; m++)
#pragma unroll
        for (int n = 0; n < 4; n++) acc[m][n] = (f32x4){0.f, 0.f, 0.f, 0.f};

    const char* Abase = Ap + (size_t)mt * 16 * TILE_BYTES;
    const char* Bbase = Bp + (size_t)nt * KT_TILES * TILE_BYTES;

    for (int kt = 0; kt < KT_TILES; kt++) {
        int akt = (kt < 16) ? (kt & 7) : (kt - 8);
        const char* gA = Abase + (size_t)akt * TILE_BYTES;
        const char* gB = Bbase + (size_t)kt * TILE_BYTES;
        __syncthreads();
#pragma unroll
        for (int i = 0; i < 4; i++) {
            int chunk = (w * 4 + i) * 1024;
            __builtin_amdgcn_global_load_lds(
                (const __attribute__((address_space(1))) void*)(gA + chunk + lane * 16),
                (__attribute__((address_space(3))) void*)&lds[chunk], 16, 0, 0);
            __builtin_amdgcn_global_load_lds(
                (const __attribute__((address_space(1))) void*)(gB + chunk + lane * 16),
                (__attribute__((address_space(3))) void*)&lds[16384 + chunk], 16, 0, 0);
        }
        __syncthreads();
#pragma unroll
        for (int kk = 0; kk < 2; kk++) {
            bf16x8 af[4], bfr[4];
#pragma unroll
            for (int m = 0; m < 4; m++) {
                int row = wr * 64 + m * 16 + (lane & 15);
                int u = kk * 4 + (lane >> 4);
                af[m] = *(const bf16x8*)&lds[row * 128 + ((u ^ (row & 7)) << 4)];
            }
#pragma unroll
            for (int n = 0; n < 4; n++) {
                int row = wc * 64 + n * 16 + (lane & 15);
                int u = kk * 4 + (lane >> 4);
                bfr[n] = *(const bf16x8*)&lds[16384 + row * 128 + ((u ^ (row & 7)) << 4)];
            }
#pragma unroll
            for (int m = 0; m < 4; m++)
#pragma unroll
                for (int n = 0; n < 4; n++)
                    acc[m][n] = __builtin_amdgcn_mfma_f32_16x16x32_bf16(af[m], bfr[n], acc[m][n], 0, 0, 0);
        }
    }

    // epilogue: per-row argmin (best, idx, second) over this block's 128 codes
    __syncthreads();
    float* rb = (float*)lds;            // [0,1K)  : 256 entries
    int* ri = (int*)(lds + 1024);       // [1K,2K)
    float* rs = (float*)(lds + 2048);   // [2K,3K)

    float e2v[4];
#pragma unroll
    for (int n = 0; n < 4; n++)
        e2v[n] = e2[nt * 128 + wc * 64 + n * 16 + (lane & 15)];

#pragma unroll
    for (int m = 0; m < 4; m++) {
#pragma unroll
        for (int r = 0; r < 4; r++) {
            float b = 3.4e38f, s = 3.4e38f;
            int bi = 1 << 30;
#pragma unroll
            for (int n = 0; n < 4; n++) {
                float v = e2v[n] - 2.f * acc[m][n][r];
                int vi = wc * 64 + n * 16 + (lane & 15);
                if (v < b || (v == b && vi < bi)) { s = b; b = v; bi = vi; }
                else s = fminf(s, v);
            }
#pragma unroll
            for (int mask = 1; mask <= 8; mask <<= 1) {
                float ob = __shfl_xor(b, mask);
                int obi = __shfl_xor(bi, mask);
                float os = __shfl_xor(s, mask);
                if (ob < b || (ob == b && obi < bi)) {
                    s = fminf(b, os); b = ob; bi = obi;
                } else {
                    s = fminf(s, ob);
                }
            }
            if ((lane & 15) == 0) {
                int rl = wr * 64 + m * 16 + (lane >> 4) * 4 + r;
                int slot = wc * 128 + rl;
                rb[slot] = b; ri[slot] = nt * 128 + bi; rs[slot] = s;
            }
        }
    }
    __syncthreads();
    if (tid < 128) {
        float b1 = rb[tid], s1 = rs[tid];
        int i1 = ri[tid];
        float b2 = rb[128 + tid], s2 = rs[128 + tid];
        int i2 = ri[128 + tid];
        float b, s; int bi;
        if (b2 < b1 || (b2 == b1 && i2 < i1)) { b = b2; bi = i2; s = fminf(s2, b1); }
        else { b = b1; bi = i1; s = fminf(s1, b2); }
        size_t gr = (size_t)mt * 128 + tid;
        pb[(size_t)nt * NROWS + gr] = b;
        pi[(size_t)nt * NROWS + gr] = bi;
        ps[(size_t)nt * NROWS + gr] = s;
    }
}

// ---------------- kernel: reduce partials -> codes + flagged rows ----------------
__global__ __launch_bounds__(256) void k_reduce(const float* __restrict__ pb,
                                                const int* __restrict__ pi,
                                                const float* __restrict__ ps,
                                                int* __restrict__ codes,
                                                int* __restrict__ list,
                                                int* __restrict__ counter) {
    int row = blockIdx.x * 256 + threadIdx.x;
    float b = 3.4e38f, s = 3.4e38f;
    int bi = 1 << 30;
    for (int nt = 0; nt < NT_TILES; nt++) {
        float b2 = pb[(size_t)nt * NROWS + row];
        int i2 = pi[(size_t)nt * NROWS + row];
        float s2 = ps[(size_t)nt * NROWS + row];
        if (b2 < b || (b2 == b && i2 < bi)) { s = fminf(b, s2); b = b2; bi = i2; }
        else s = fminf(s, b2);
    }
    codes[row] = bi;
    if (s - b < REFINE_THR) {
        int p = atomicAdd(counter, 1);
        list[p] = row;
    }
}

// ---------------- kernel: fp64 full-scan refine of flagged rows ----------------
__global__ __launch_bounds__(256) void k_refine(const float* __restrict__ x,
                                                const float* __restrict__ emb,
                                                int* __restrict__ codes,
                                                const int* __restrict__ list,
                                                const int* __restrict__ counter) {
    __shared__ float xrow[DS];
    __shared__ double redv[256];
    __shared__ int redi[256];
    int tid = threadIdx.x;
    int nflag = *counter;
    for (int it = blockIdx.x; it < nflag; it += gridDim.x) {
        int row = list[it];
        int b = row >> 12;
        int t = row & 4095;
        for (int d = tid; d < DS; d += 256)
            xrow[d] = x[((size_t)b * DTOT + d) * TT_DIM + t];
        __syncthreads();
        double bv = 1e300;
        int bi = 1 << 30;
        for (int c = tid; c < NCODES; c += 256) {
            const float* er = emb + (size_t)c * DS;
            double s = 0.0;
            for (int d = 0; d < DS; d += 4) {
                float4 ev = *(const float4*)&er[d];
                float4 xv = *(const float4*)&xrow[d];
                double d0 = (double)xv.x - (double)ev.x;
                double d1 = (double)xv.y - (double)ev.y;
                double d2 = (double)xv.z - (double)ev.z;
                double d3 = (double)xv.w - (double)ev.w;
                s += d0 * d0 + d1 * d1 + d2 * d2 + d3 * d3;
            }
            if (s < bv || (s == bv && c < bi)) { bv = s; bi = c; }
        }
        redv[tid] = bv; redi[tid] = bi;
        __syncthreads();
        for (int off = 128; off; off >>= 1) {
            if (tid < off) {
                if (redv[tid + off] < redv[tid] ||
                    (redv[tid + off] == redv[tid] && redi[tid + off] < redi[tid])) {
                    redv[tid] = redv[tid + off];
                    redi[tid] = redi[tid + off];
                }
            }
            __syncthreads();
        }
        if (tid == 0) codes[row] = redi[0];
        __syncthreads();
    }
}

// ---------------- kernel: sem output (gather or copy) + sem codes ----------------
__global__ __launch_bounds__(256) void k_sem(const float* __restrict__ x,
                                             const float* __restrict__ emb,
                                             const int* __restrict__ codes,
                                             const float* __restrict__ sem_probs,
                                             float* __restrict__ out) {
    __shared__ float q[TT * (DS + 1)];
    __shared__ int rowc[TT];
    int b = blockIdx.y, t0 = blockIdx.x * TT;
    bool mask = sem_probs[b] < 0.5f;
    float* outb = out + (size_t)b * DTOT * TT_DIM + t0;
    const float* xb = x + (size_t)b * DTOT * TT_DIM + t0;
    const size_t QOFF = (size_t)BB * DTOT * TT_DIM;

    if (threadIdx.x < TT) {
        int code = codes[b * TT_DIM + t0 + threadIdx.x];
        rowc[threadIdx.x] = code;
        out[QOFF + ((size_t)b * 33) * TT_DIM + t0 + threadIdx.x] = (float)code;
    }
    __syncthreads();

    if (mask) {
        for (int i = 0; i < TT * DS / 256; i++) {
            int idx = threadIdx.x + i * 256;
            int tt = idx >> 9, d = idx & 511;
            q[tt * (DS + 1) + d] = emb[(size_t)rowc[tt] * DS + d];
        }
        __syncthreads();
        for (int i = 0; i < TT * DS / 256; i++) {
            int idx = threadIdx.x + i * 256;
            int d = idx >> 5, tt = idx & 31;
            outb[(size_t)d * TT_DIM + tt] = q[tt * (DS + 1) + d];
        }
    } else {
        for (int i = 0; i < TT * DS / 256; i++) {
            int idx = threadIdx.x + i * 256;
            int d = idx >> 5, tt = idx & 31;
            outb[(size_t)d * TT_DIM + tt] = xb[(size_t)d * TT_DIM + tt];
        }
    }
}

// ---------------- kernel: aco elementwise ----------------
__global__ __launch_bounds__(256) void k_aco(const float* __restrict__ x,
                                             const float* __restrict__ noise,
                                             const float* __restrict__ aco_probs,
                                             float* __restrict__ out) {
    int idx = blockIdx.x * 256 + threadIdx.x;
    int t4 = idx & 1023;
    int bc = idx >> 10;
    int ch = bc & 31;
    int b = bc >> 5;
    const float4 xv = *(const float4*)&x[((size_t)(b * DTOT + DS + ch)) * TT_DIM + t4 * 4];
    const float4 nv = *(const float4*)&noise[((size_t)(b * 32 + ch)) * TT_DIM + t4 * 4];
    float p = aco_probs[b];
    const size_t QOFF = (size_t)BB * DTOT * TT_DIM;

    float zq[4], cq[4];
    float xa[4] = {xv.x, xv.y, xv.z, xv.w};
    float na[4] = {nv.x, nv.y, nv.z, nv.w};
#pragma unroll
    for (int i = 0; i < 4; i++) {
        float zb = tanhf(xa[i]) * HALFV;
        float z;
        if (p < 0.5f) z = rintf(zb);
        else if (p < 0.75f) z = fminf(fmaxf(zb + na[i], -HALFV), HALFV);
        else z = zb;
        zq[i] = z / HALFV;
        cq[i] = fminf(fmaxf(rintf(z + HALFV), 0.f), 15.f);
    }
    float4 qo = {zq[0], zq[1], zq[2], zq[3]};
    float4 co = {cq[0], cq[1], cq[2], cq[3]};
    *(float4*)&out[((size_t)(b * DTOT + DS + ch)) * TT_DIM + t4 * 4] = qo;
    *(float4*)&out[QOFF + ((size_t)(b * 33 + 1 + ch)) * TT_DIM + t4 * 4] = co;
}

extern "C" void kernel_launch(void* const* d_in, const int* in_sizes, int n_in,
                              void* d_out, int out_size, void* d_ws, size_t ws_size,
                              hipStream_t stream) {
    const float* x         = (const float*)d_in[0];
    const float* esum      = (const float*)d_in[1];
    const float* usage     = (const float*)d_in[2];
    const float* sem_probs = (const float*)d_in[3];
    const float* aco_probs = (const float*)d_in[4];
    const float* noise     = (const float*)d_in[5];
    float* out = (float*)d_out;

    char* w = (char*)d_ws;
    float* emb    = (float*)w;                         // 8,388,608 B
    float* e2     = (float*)(w + 8388608);             // 16,384 B
    char*  Ap     = w + 8404992;                       // 134,217,728 B
    char*  Bp     = w + 142622720;                     // 12,582,912 B
    float* pb     = (float*)(w + 155205632);           // 8,388,608 B
    int*   pi     = (int*)(w + 163594240);             // 8,388,608 B
    float* ps     = (float*)(w + 171982848);           // 8,388,608 B
    int*   codes  = (int*)(w + 180371456);             // 262,144 B
    int*   list   = (int*)(w + 180633600);             // 262,144 B
    int*   counter= (int*)(w + 180895744);             // 4 B

    k_emb<<<NCODES, 256, 0, stream>>>(esum, usage, emb, e2, counter);
    k_packA<<<dim3(MT_TILES, 8), 256, 0, stream>>>(x, Ap);
    k_packB<<<dim3(NT_TILES, KT_TILES), 256, 0, stream>>>(emb, Bp);
    k_mfma<<<dim3(NT_TILES, MT_TILES), 256, 0, stream>>>(Ap, Bp, e2, pb, pi, ps);
    k_reduce<<<NROWS / 256, 256, 0, stream>>>(pb, pi, ps, codes, list, counter);
    k_refine<<<256, 256, 0, stream>>>(x, emb, codes, list, counter);
    k_sem<<<dim3(TT_DIM / TT, BB), 256, 0, stream>>>(x, emb, codes, sem_probs, out);
    k_aco<<<(BB * 32 * TT_DIM) / (256 * 4), 256, 0, stream>>>(x, noise, aco_probs, out);
}

// Round 4
// 1310.317 us; speedup vs baseline: 3.7078x; 1.0641x over previous
//
#include <hip/hip_runtime.h>
#include <math.h>

#define BB 16
#define DTOT 544
#define TT_DIM 4096
#define DS 512
#define NCODES 4096
#define HALFV 7.5f
#define EPSV 1e-5f
#define NROWS (BB * TT_DIM)          // 65536
#define NT 16                        // 4096 / 256
#define MT 256                       // 65536 / 256
#define REFINE_THR 0.05f
#define TT 32                        // t per block in k_sem

typedef short bf16x8 __attribute__((ext_vector_type(8)));
typedef float f32x4 __attribute__((ext_vector_type(4)));

__device__ __forceinline__ unsigned short f2bf(float v) {
    unsigned u = __float_as_uint(v);
    unsigned r = (u + 0x7fffu + ((u >> 16) & 1u)) >> 16;
    return (unsigned short)r;
}
__device__ __forceinline__ float bf2f(unsigned short h) {
    return __uint_as_float((unsigned)h << 16);
}

// ---------------- kernel: emb fp32 + e2 + zero flag counter ----------------
__global__ __launch_bounds__(256) void k_emb(const float* __restrict__ esum,
                                             const float* __restrict__ usage,
                                             float* __restrict__ emb,
                                             float* __restrict__ e2,
                                             int* __restrict__ counter) {
    int c = blockIdx.x;
    if (c == 0 && threadIdx.x == 0) *counter = 0;
    float u = usage[c];
    u = (u < EPSV) ? EPSV : u;
    float s = 0.f;
#pragma unroll
    for (int i = 0; i < 2; i++) {
        int d = threadIdx.x + i * 256;
        float v = esum[(size_t)c * DS + d] / u;
        emb[(size_t)c * DS + d] = v;
        s += v * v;
    }
#pragma unroll
    for (int o = 32; o; o >>= 1) s += __shfl_down(s, o, 64);
    __shared__ float red[4];
    if ((threadIdx.x & 63) == 0) red[threadIdx.x >> 6] = s;
    __syncthreads();
    if (threadIdx.x == 0) e2[c] = red[0] + red[1] + red[2] + red[3];
}

// ---------------- pack A: x sem -> 256row x 32K bf16 tiles (chunks: 16 hi, 16 lo) ----------------
// tile byte layout (matches LDS image): off = row*64 + ((u ^ ((row>>1)&3))<<4) + (k&7)*2, u = k>>3
__global__ __launch_bounds__(256) void k_packA(const float* __restrict__ x,
                                               char* __restrict__ Ap) {
    __shared__ char ldsH[16384];
    __shared__ char ldsL[16384];
    int mt = blockIdx.x, dc = blockIdx.y;
    int b = mt >> 4;
    int t0 = (mt & 15) * 256;
    int tid = threadIdx.x;
#pragma unroll
    for (int i = 0; i < 8; i++) {
        int idx = tid + i * 256;
        int d = idx >> 6;            // 0..31
        int t4 = idx & 63;           // 0..63
        float4 v = *(const float4*)&x[((size_t)b * DTOT + dc * 32 + d) * TT_DIM + t0 + t4 * 4];
        float va[4] = {v.x, v.y, v.z, v.w};
        int u = d >> 3;
        int kb = (d & 7) * 2;
#pragma unroll
        for (int j = 0; j < 4; j++) {
            int row = t4 * 4 + j;
            unsigned short hi = f2bf(va[j]);
            unsigned short lo = f2bf(va[j] - bf2f(hi));
            int off = row * 64 + ((u ^ ((row >> 1) & 3)) << 4) + kb;
            *(unsigned short*)&ldsH[off] = hi;
            *(unsigned short*)&ldsL[off] = lo;
        }
    }
    __syncthreads();
    char* gH = Ap + ((size_t)mt * 32 + dc) * 16384;
    char* gL = Ap + ((size_t)mt * 32 + 16 + dc) * 16384;
#pragma unroll
    for (int i = 0; i < 4; i++) {
        int off = (tid + i * 256) * 16;
        *(uint4*)&gH[off] = *(const uint4*)&ldsH[off];
        *(uint4*)&gL[off] = *(const uint4*)&ldsL[off];
    }
}

// ---------------- pack B: emb -> 256code x 32K bf16 tiles (chunks: 16 hi, 16 lo) ----------------
__global__ __launch_bounds__(256) void k_packB(const float* __restrict__ emb,
                                               char* __restrict__ Bp) {
    __shared__ char ldsT[16384];
    int nt = blockIdx.x, c = blockIdx.y;
    int lo_flag = (c >= 16);
    int d0 = (lo_flag ? (c - 16) : c) * 32;
    int c0 = nt * 256;
    int tid = threadIdx.x;
#pragma unroll
    for (int i = 0; i < 8; i++) {
        int idx = tid + i * 256;
        int row = idx >> 3;          // code 0..255
        int f4 = idx & 7;            // d-float4 0..7
        float4 v = *(const float4*)&emb[(size_t)(c0 + row) * DS + d0 + f4 * 4];
        float va[4] = {v.x, v.y, v.z, v.w};
        unsigned short wv[4];
#pragma unroll
        for (int j = 0; j < 4; j++) {
            unsigned short hi = f2bf(va[j]);
            wv[j] = lo_flag ? f2bf(va[j] - bf2f(hi)) : hi;
        }
        int u = f4 >> 1;
        int off = row * 64 + ((u ^ ((row >> 1) & 3)) << 4) + (f4 & 1) * 8;
        uint2 pk;
        pk.x = ((unsigned)wv[1] << 16) | wv[0];
        pk.y = ((unsigned)wv[3] << 16) | wv[2];
        *(uint2*)&ldsT[off] = pk;
    }
    __syncthreads();
    char* g = Bp + ((size_t)nt * 32 + c) * 16384;
#pragma unroll
    for (int i = 0; i < 4; i++) {
        int off = (tid + i * 256) * 16;
        *(uint4*)&g[off] = *(const uint4*)&ldsT[off];
    }
}

// ---------------- MFMA distance-argmin: 256x256 tile, BK=64, 2-slot dbuf, 1 sync/tile ----------------
#define MM(A, B, C) __builtin_amdgcn_mfma_f32_16x16x32_bf16((A), (B), (C), 0, 0, 0)

#define GLDS(SRC, DOFF)                                                              \
    __builtin_amdgcn_global_load_lds(                                                \
        (const __attribute__((address_space(1))) void*)(SRC),                        \
        (__attribute__((address_space(3))) void*)&lds[DOFF], 16, 0, 0)

// stage 64-K tile KT (two 32-K chunks) into slot at byte SB
#define STAGE(KT, SB) do {                                                           \
    _Pragma("unroll")                                                                \
    for (int s_ = 0; s_ < 2; s_++) {                                                 \
        int k32_ = 2 * (KT) + s_;                                                    \
        int akt_ = (k32_ < 32) ? (k32_ & 15) : (k32_ - 16);                          \
        int bkt_ = (k32_ < 32) ? k32_ : (k32_ - 32);                                 \
        const char* sa_ = Ap_mt + akt_ * 16384 + wl;                                 \
        const char* sb_ = Bp_nt + bkt_ * 16384 + wl;                                 \
        GLDS(sa_,        (SB) + s_ * 16384 + w2048);                                 \
        GLDS(sa_ + 1024, (SB) + s_ * 16384 + w2048 + 1024);                          \
        GLDS(sb_,        (SB) + 32768 + s_ * 16384 + w2048);                         \
        GLDS(sb_ + 1024, (SB) + 32768 + s_ * 16384 + w2048 + 1024);                  \
    }                                                                                \
} while (0)

__global__ __launch_bounds__(512) void k_mfma(const char* __restrict__ Ap,
                                              const char* __restrict__ Bp,
                                              const float* __restrict__ e2,
                                              float* __restrict__ pb,
                                              int* __restrict__ pi,
                                              float* __restrict__ ps) {
    extern __shared__ char lds[];
    // XCD-bijective swizzle: 4096 blocks, 8 XCDs -> 512 consecutive lin per XCD
    int bid = blockIdx.x;
    int lin = (bid >> 3) + (bid & 7) * 512;
    int nt = lin & 15;
    int mt = lin >> 4;

    int tid = threadIdx.x;
    int lane = tid & 63;
    int w = tid >> 6;
    int wr = w >> 2, wc = w & 3;
    int l15 = lane & 15, lhi = lane >> 4;
    int w2048 = w * 2048;
    int wl = w2048 + lane * 16;

    const char* Ap_mt = Ap + (size_t)mt * 32 * 16384;
    const char* Bp_nt = Bp + (size_t)nt * 32 * 16384;

    // per-lane swizzled fragment byte offsets (within a 16KB 32-K chunk)
    int offA[8], offB[4];
#pragma unroll
    for (int m = 0; m < 8; m++) {
        int r = wr * 128 + m * 16 + l15;
        offA[m] = r * 64 + ((lhi ^ ((r >> 1) & 3)) << 4);
    }
#pragma unroll
    for (int n = 0; n < 4; n++) {
        int r = wc * 64 + n * 16 + l15;
        offB[n] = r * 64 + ((lhi ^ ((r >> 1) & 3)) << 4);
    }

    f32x4 acc[8][4];
#pragma unroll
    for (int m = 0; m < 8; m++)
#pragma unroll
        for (int n = 0; n < 4; n++) acc[m][n] = (f32x4){0.f, 0.f, 0.f, 0.f};

    STAGE(0, 0);
    int cur = 0;
#pragma unroll 1
    for (int kt = 0; kt < 24; kt++) {
        __syncthreads();   // drains vmcnt(0)+lgkmcnt(0): slot[cur] staged & visible; prev reads done
        if (kt + 1 < 24) STAGE(kt + 1, (cur ^ 1) * 65536);
        int sb = cur * 65536;
#pragma unroll
        for (int s = 0; s < 2; s++) {
            bf16x8 af[8], bf[4];
#pragma unroll
            for (int m = 0; m < 8; m++)
                af[m] = *(const bf16x8*)&lds[sb + s * 16384 + offA[m]];
#pragma unroll
            for (int n = 0; n < 4; n++)
                bf[n] = *(const bf16x8*)&lds[sb + 32768 + s * 16384 + offB[n]];
            __builtin_amdgcn_s_setprio(1);
#pragma unroll
            for (int m = 0; m < 8; m++)
#pragma unroll
                for (int n = 0; n < 4; n++)
                    acc[m][n] = MM(af[m], bf[n], acc[m][n]);
            __builtin_amdgcn_s_setprio(0);
        }
        cur ^= 1;
    }

    // ---------------- epilogue: per-row argmin ----------------
    __syncthreads();
    float* rb = (float*)lds;
    float* rs = (float*)(lds + 4096);
    int*   ri = (int*)(lds + 8192);

    float e2v[4];
#pragma unroll
    for (int n = 0; n < 4; n++)
        e2v[n] = e2[nt * 256 + wc * 64 + n * 16 + l15];

#pragma unroll
    for (int m = 0; m < 8; m++) {
#pragma unroll
        for (int r2 = 0; r2 < 4; r2++) {
            float bst = 3.4e38f, sec = 3.4e38f;
            int bi = 1 << 30;
#pragma unroll
            for (int n = 0; n < 4; n++) {
                float v = e2v[n] - 2.f * acc[m][n][r2];
                int vi = wc * 64 + n * 16 + l15;
                if (v < bst || (v == bst && vi < bi)) { sec = bst; bst = v; bi = vi; }
                else sec = fminf(sec, v);
            }
#pragma unroll
            for (int mask = 1; mask <= 8; mask <<= 1) {
                float ob = __shfl_xor(bst, mask);
                int obi = __shfl_xor(bi, mask);
                float os = __shfl_xor(sec, mask);
                if (ob < bst || (ob == bst && obi < bi)) {
                    sec = fminf(bst, os); bst = ob; bi = obi;
                } else {
                    sec = fminf(sec, ob);
                }
            }
            if (l15 == 0) {
                int rl = wr * 128 + m * 16 + lhi * 4 + r2;
                int slot = wc * 256 + rl;
                rb[slot] = bst; rs[slot] = sec; ri[slot] = nt * 256 + bi;
            }
        }
    }
    __syncthreads();
    if (tid < 256) {
        float bsv = rb[tid], ssv = rs[tid];
        int biv = ri[tid];
#pragma unroll
        for (int c = 1; c < 4; c++) {
            float ob = rb[c * 256 + tid];
            float os = rs[c * 256 + tid];
            int oi = ri[c * 256 + tid];
            if (ob < bsv || (ob == bsv && oi < biv)) { ssv = fminf(bsv, os); bsv = ob; biv = oi; }
            else ssv = fminf(ssv, ob);
        }
        size_t gr = (size_t)mt * 256 + tid;
        pb[(size_t)nt * NROWS + gr] = bsv;
        pi[(size_t)nt * NROWS + gr] = biv;
        ps[(size_t)nt * NROWS + gr] = ssv;
    }
}

// ---------------- reduce partials -> codes + flagged rows ----------------
__global__ __launch_bounds__(256) void k_reduce(const float* __restrict__ pb,
                                                const int* __restrict__ pi,
                                                const float* __restrict__ ps,
                                                int* __restrict__ codes,
                                                int* __restrict__ list,
                                                int* __restrict__ counter) {
    int row = blockIdx.x * 256 + threadIdx.x;
    float b = 3.4e38f, s = 3.4e38f;
    int bi = 1 << 30;
    for (int nt = 0; nt < NT; nt++) {
        float b2 = pb[(size_t)nt * NROWS + row];
        int i2 = pi[(size_t)nt * NROWS + row];
        float s2 = ps[(size_t)nt * NROWS + row];
        if (b2 < b || (b2 == b && i2 < bi)) { s = fminf(b, s2); b = b2; bi = i2; }
        else s = fminf(s, b2);
    }
    codes[row] = bi;
    if (s - b < REFINE_THR) {
        int p = atomicAdd(counter, 1);
        list[p] = row;
    }
}

// ---------------- fp64 full-scan refine of flagged rows ----------------
__global__ __launch_bounds__(256) void k_refine(const float* __restrict__ x,
                                                const float* __restrict__ emb,
                                                int* __restrict__ codes,
                                                const int* __restrict__ list,
                                                const int* __restrict__ counter) {
    __shared__ float xrow[DS];
    __shared__ double redv[256];
    __shared__ int redi[256];
    int tid = threadIdx.x;
    int nflag = *counter;
    for (int it = blockIdx.x; it < nflag; it += gridDim.x) {
        int row = list[it];
        int b = row >> 12;
        int t = row & 4095;
        for (int d = tid; d < DS; d += 256)
            xrow[d] = x[((size_t)b * DTOT + d) * TT_DIM + t];
        __syncthreads();
        double bv = 1e300;
        int bi = 1 << 30;
        for (int c = tid; c < NCODES; c += 256) {
            const float* er = emb + (size_t)c * DS;
            double s = 0.0;
            for (int d = 0; d < DS; d += 4) {
                float4 ev = *(const float4*)&er[d];
                float4 xv = *(const float4*)&xrow[d];
                double d0 = (double)xv.x - (double)ev.x;
                double d1 = (double)xv.y - (double)ev.y;
                double d2 = (double)xv.z - (double)ev.z;
                double d3 = (double)xv.w - (double)ev.w;
                s += d0 * d0 + d1 * d1 + d2 * d2 + d3 * d3;
            }
            if (s < bv || (s == bv && c < bi)) { bv = s; bi = c; }
        }
        redv[tid] = bv; redi[tid] = bi;
        __syncthreads();
        for (int off = 128; off; off >>= 1) {
            if (tid < off) {
                if (redv[tid + off] < redv[tid] ||
                    (redv[tid + off] == redv[tid] && redi[tid + off] < redi[tid])) {
                    redv[tid] = redv[tid + off];
                    redi[tid] = redi[tid + off];
                }
            }
            __syncthreads();
        }
        if (tid == 0) codes[row] = redi[0];
        __syncthreads();
    }
}

// ---------------- sem output (gather or copy) + sem codes ----------------
__global__ __launch_bounds__(256) void k_sem(const float* __restrict__ x,
                                             const float* __restrict__ emb,
                                             const int* __restrict__ codes,
                                             const float* __restrict__ sem_probs,
                                             float* __restrict__ out) {
    __shared__ float q[TT * (DS + 1)];
    __shared__ int rowc[TT];
    int b = blockIdx.y, t0 = blockIdx.x * TT;
    bool mask = sem_probs[b] < 0.5f;
    float* outb = out + (size_t)b * DTOT * TT_DIM + t0;
    const float* xb = x + (size_t)b * DTOT * TT_DIM + t0;
    const size_t QOFF = (size_t)BB * DTOT * TT_DIM;

    if (threadIdx.x < TT) {
        int code = codes[b * TT_DIM + t0 + threadIdx.x];
        rowc[threadIdx.x] = code;
        out[QOFF + ((size_t)b * 33) * TT_DIM + t0 + threadIdx.x] = (float)code;
    }
    __syncthreads();

    if (mask) {
        for (int i = 0; i < TT * DS / 256; i++) {
            int idx = threadIdx.x + i * 256;
            int tt = idx >> 9, d = idx & 511;
            q[tt * (DS + 1) + d] = emb[(size_t)rowc[tt] * DS + d];
        }
        __syncthreads();
        for (int i = 0; i < TT * DS / 256; i++) {
            int idx = threadIdx.x + i * 256;
            int d = idx >> 5, tt = idx & 31;
            outb[(size_t)d * TT_DIM + tt] = q[tt * (DS + 1) + d];
        }
    } else {
        for (int i = 0; i < TT * DS / 256; i++) {
            int idx = threadIdx.x + i * 256;
            int d = idx >> 5, tt = idx & 31;
            outb[(size_t)d * TT_DIM + tt] = xb[(size_t)d * TT_DIM + tt];
        }
    }
}

// ---------------- aco elementwise ----------------
__global__ __launch_bounds__(256) void k_aco(const float* __restrict__ x,
                                             const float* __restrict__ noise,
                                             const float* __restrict__ aco_probs,
                                             float* __restrict__ out) {
    int idx = blockIdx.x * 256 + threadIdx.x;
    int t4 = idx & 1023;
    int bc = idx >> 10;
    int ch = bc & 31;
    int b = bc >> 5;
    const float4 xv = *(const float4*)&x[((size_t)(b * DTOT + DS + ch)) * TT_DIM + t4 * 4];
    const float4 nv = *(const float4*)&noise[((size_t)(b * 32 + ch)) * TT_DIM + t4 * 4];
    float p = aco_probs[b];
    const size_t QOFF = (size_t)BB * DTOT * TT_DIM;

    float zq[4], cq[4];
    float xa[4] = {xv.x, xv.y, xv.z, xv.w};
    float na[4] = {nv.x, nv.y, nv.z, nv.w};
#pragma unroll
    for (int i = 0; i < 4; i++) {
        float zb = tanhf(xa[i]) * HALFV;
        float z;
        if (p < 0.5f) z = rintf(zb);
        else if (p < 0.75f) z = fminf(fmaxf(zb + na[i], -HALFV), HALFV);
        else z = zb;
        zq[i] = z / HALFV;
        cq[i] = fminf(fmaxf(rintf(z + HALFV), 0.f), 15.f);
    }
    float4 qo = {zq[0], zq[1], zq[2], zq[3]};
    float4 co = {cq[0], cq[1], cq[2], cq[3]};
    *(float4*)&out[((size_t)(b * DTOT + DS + ch)) * TT_DIM + t4 * 4] = qo;
    *(float4*)&out[QOFF + ((size_t)(b * 33 + 1 + ch)) * TT_DIM + t4 * 4] = co;
}

extern "C" void kernel_launch(void* const* d_in, const int* in_sizes, int n_in,
                              void* d_out, int out_size, void* d_ws, size_t ws_size,
                              hipStream_t stream) {
    const float* x         = (const float*)d_in[0];
    const float* esum      = (const float*)d_in[1];
    const float* usage     = (const float*)d_in[2];
    const float* sem_probs = (const float*)d_in[3];
    const float* aco_probs = (const float*)d_in[4];
    const float* noise     = (const float*)d_in[5];
    float* out = (float*)d_out;

    char* w = (char*)d_ws;
    float* emb    = (float*)w;                         // 8,388,608
    float* e2     = (float*)(w + 8388608);             // 16,384
    char*  Ap     = w + 8404992;                       // 134,217,728
    char*  Bp     = w + 142622720;                     // 8,388,608
    float* pb     = (float*)(w + 151011328);           // 4,194,304
    int*   pi     = (int*)(w + 155205632);             // 4,194,304
    float* ps     = (float*)(w + 159399936);           // 4,194,304
    int*   codes  = (int*)(w + 163594240);             // 262,144
    int*   list   = (int*)(w + 163856384);             // 262,144
    int*   counter= (int*)(w + 164118528);             // 4

    k_emb<<<NCODES, 256, 0, stream>>>(esum, usage, emb, e2, counter);
    k_packA<<<dim3(MT, 16), 256, 0, stream>>>(x, Ap);
    k_packB<<<dim3(NT, 32), 256, 0, stream>>>(emb, Bp);
    k_mfma<<<NT * MT, 512, 131072, stream>>>(Ap, Bp, e2, pb, pi, ps);
    k_reduce<<<NROWS / 256, 256, 0, stream>>>(pb, pi, ps, codes, list, counter);
    k_refine<<<256, 256, 0, stream>>>(x, emb, codes, list, counter);
    k_sem<<<dim3(TT_DIM / TT, BB), 256, 0, stream>>>(x, emb, codes, sem_probs, out);
    k_aco<<<(BB * 32 * TT_DIM) / (256 * 4), 256, 0, stream>>>(x, noise, aco_probs, out);
}